// Round 1
// baseline (2132.872 us; speedup 1.0000x reference)
//
#include <hip/hip_runtime.h>
#include <math.h>

#define B_ 64
#define T_ 12
#define N_ 307
#define I_ 3
#define R_ 64
#define D_ 10
#define M_ (B_*N_)      // 19648
#define TM_ (T_*M_)     // 235776

__device__ __forceinline__ float sigm(float x){ return 1.f/(1.f+__expf(-x)); }

// ---------------- stage A: x-embedding MLP + feature gram + fc1 MLP -> g1_in [T][M][10]
__global__ __launch_bounds__(256) void k_stageA(
    const float* __restrict__ x,
    const float* __restrict__ xw1, const float* __restrict__ xb1,
    const float* __restrict__ xw2, const float* __restrict__ xb2,
    const float* __restrict__ xw3, const float* __restrict__ xb3,
    const float* __restrict__ fw1, const float* __restrict__ fb1,
    const float* __restrict__ fw2, const float* __restrict__ fb2,
    const float* __restrict__ fw3, const float* __restrict__ fb3,
    float* __restrict__ g1)
{
  int idx = blockIdx.x*256 + threadIdx.x;      // t*M + m, exact grid
  int t = idx / M_;
  int m = idx - t*M_;
  int b = m / N_;
  int n = m - b*N_;
  const float* xp = x + (((size_t)b*T_ + t)*N_ + n)*I_;
  float xv[3] = {xp[0], xp[1], xp[2]};
  float e[3][10];
  #pragma unroll
  for (int i=0;i<3;++i){
    float h1[16];
    #pragma unroll
    for (int u=0;u<16;++u) h1[u] = sigm(xv[i]*xw1[u] + xb1[u]);
    float h2[2];
    #pragma unroll
    for (int v=0;v<2;++v){
      float a = xb2[v];
      #pragma unroll
      for (int u=0;u<16;++u) a += h1[u]*xw2[v*16+u];
      h2[v] = sigm(a);
    }
    #pragma unroll
    for (int d=0;d<10;++d) e[i][d] = xb3[d] + h2[0]*xw3[d*2] + h2[1]*xw3[d*2+1];
  }
  float in1[3];
  #pragma unroll
  for (int j=0;j<3;++j){
    float acc = 0.f;
    #pragma unroll
    for (int i=0;i<3;++i){
      float s = 0.f;
      #pragma unroll
      for (int d=0;d<10;++d) s += e[j][d]*e[i][d];
      s = fmaxf(s, 0.f);
      acc += s*xv[i];
    }
    in1[j] = xv[j] + acc;
  }
  float h1[16];
  #pragma unroll
  for (int u=0;u<16;++u)
    h1[u] = sigm(fb1[u] + in1[0]*fw1[u*3] + in1[1]*fw1[u*3+1] + in1[2]*fw1[u*3+2]);
  float h2[2];
  #pragma unroll
  for (int v=0;v<2;++v){
    float a = fb2[v];
    #pragma unroll
    for (int u=0;u<16;++u) a += h1[u]*fw2[v*16+u];
    h2[v] = sigm(a);
  }
  float* gp = g1 + (size_t)idx*10;
  #pragma unroll
  for (int d=0;d<10;++d) gp[d] = fb3[d] + h2[0]*fw3[d*2] + h2[1]*fw3[d*2+1];
}

// ---------------- per-node mixing matrices: Wn [N][64*64] (layout [c][r]), bn [N][64]
__global__ __launch_bounds__(256) void k_wn(
    const float* __restrict__ emb2, const float* __restrict__ wpool,
    const float* __restrict__ bpool, float* __restrict__ Wn, float* __restrict__ bn)
{
  int n = blockIdx.x; int tid = threadIdx.x;
  __shared__ float e_s[10];
  if (tid < 10) e_s[tid] = emb2[n*10 + tid];
  __syncthreads();
  #pragma unroll
  for (int e=0;e<16;++e){
    int i = e*256 + tid;            // 0..4095
    float a = 0.f;
    #pragma unroll
    for (int d=0;d<10;++d) a += e_s[d]*wpool[(size_t)d*4096 + i];
    Wn[(size_t)n*4096 + i] = a;
  }
  if (tid < 64){
    float a = 0.f;
    #pragma unroll
    for (int d=0;d<10;++d) a += e_s[d]*bpool[d*64 + tid];
    bn[n*64 + tid] = a;
  }
}

// ---------------- fused GRU step: [h | x] @ [whh | wih]^T with separate h/x accumulators
// block = 64 rows x 192 cols; thread (tr,tc): rows tr*4..+3, units tc*4..+3 (all 3 gates)
template<int DIN, int KP, int KS, bool WSEQ, bool WFIN>
__global__ __launch_bounds__(256) void k_gru(
    const float* __restrict__ xin, const float* __restrict__ hprev,
    float* __restrict__ hnext,
    const float* __restrict__ wih, const float* __restrict__ whh,
    const float* __restrict__ bih, const float* __restrict__ bhh,
    float* __restrict__ oseq, float* __restrict__ ofin, int t)
{
  __shared__ __align__(16) float W_s[192*KS];
  __shared__ __align__(16) float A_s[KP*68];
  const int tid = threadIdx.x;
  const int row0 = blockIdx.x * 64;

  for (int idx = tid; idx < 192*KP; idx += 256) {
    int col = idx / KP, k = idx - col*KP;
    float v = 0.f;
    if (k < 64) v = whh[col*64 + k];
    else if (k - 64 < DIN) v = wih[col*DIN + (k-64)];
    W_s[col*KS + k] = v;
  }
  for (int idx = tid; idx < 64*64; idx += 256) {
    int row = idx >> 6, k = idx & 63;
    A_s[k*68 + row] = hprev[(size_t)(row0+row)*64 + k];
  }
  constexpr int XK = KP - 64;
  for (int idx = tid; idx < 64*XK; idx += 256) {
    int row = idx / XK, kk = idx - row*XK;
    float v = (kk < DIN) ? xin[(size_t)(row0+row)*DIN + kk] : 0.f;
    A_s[(64+kk)*68 + row] = v;
  }
  __syncthreads();

  const int tr = tid & 15, tc = tid >> 4;
  const int u0 = tc * 4;
  const int tr4 = tr * 4;

  float acc_h[4][3][4];
  float acc_x[4][3][4];
  #pragma unroll
  for (int rr=0;rr<4;++rr)
    #pragma unroll
    for (int g=0;g<3;++g)
      #pragma unroll
      for (int uu=0;uu<4;++uu){ acc_h[rr][g][uu]=0.f; acc_x[rr][g][uu]=0.f; }

  for (int k=0; k<64; k+=4) {
    float4 a0 = *(const float4*)&A_s[(k+0)*68 + tr4];
    float4 a1 = *(const float4*)&A_s[(k+1)*68 + tr4];
    float4 a2 = *(const float4*)&A_s[(k+2)*68 + tr4];
    float4 a3 = *(const float4*)&A_s[(k+3)*68 + tr4];
    #pragma unroll
    for (int g=0;g<3;++g)
      #pragma unroll
      for (int uu=0;uu<4;++uu){
        float4 w = *(const float4*)&W_s[(g*64+u0+uu)*KS + k];
        acc_h[0][g][uu] += a0.x*w.x + a1.x*w.y + a2.x*w.z + a3.x*w.w;
        acc_h[1][g][uu] += a0.y*w.x + a1.y*w.y + a2.y*w.z + a3.y*w.w;
        acc_h[2][g][uu] += a0.z*w.x + a1.z*w.y + a2.z*w.z + a3.z*w.w;
        acc_h[3][g][uu] += a0.w*w.x + a1.w*w.y + a2.w*w.z + a3.w*w.w;
      }
  }
  for (int k=64; k<KP; k+=4) {
    float4 a0 = *(const float4*)&A_s[(k+0)*68 + tr4];
    float4 a1 = *(const float4*)&A_s[(k+1)*68 + tr4];
    float4 a2 = *(const float4*)&A_s[(k+2)*68 + tr4];
    float4 a3 = *(const float4*)&A_s[(k+3)*68 + tr4];
    #pragma unroll
    for (int g=0;g<3;++g)
      #pragma unroll
      for (int uu=0;uu<4;++uu){
        float4 w = *(const float4*)&W_s[(g*64+u0+uu)*KS + k];
        acc_x[0][g][uu] += a0.x*w.x + a1.x*w.y + a2.x*w.z + a3.x*w.w;
        acc_x[1][g][uu] += a0.y*w.x + a1.y*w.y + a2.y*w.z + a3.y*w.w;
        acc_x[2][g][uu] += a0.z*w.x + a1.z*w.y + a2.z*w.z + a3.z*w.w;
        acc_x[3][g][uu] += a0.w*w.x + a1.w*w.y + a2.w*w.z + a3.w*w.w;
      }
  }

  #pragma unroll
  for (int rr=0; rr<4; ++rr) {
    int row = tr4 + rr; int grow = row0 + row;
    float o[4];
    #pragma unroll
    for (int uu=0; uu<4; ++uu) {
      int u = u0+uu;
      float xr = acc_x[rr][0][uu] + bih[u];
      float hr = acc_h[rr][0][uu] + bhh[u];
      float xz = acc_x[rr][1][uu] + bih[64+u];
      float hz = acc_h[rr][1][uu] + bhh[64+u];
      float xn = acc_x[rr][2][uu] + bih[128+u];
      float hn = acc_h[rr][2][uu] + bhh[128+u];
      float rg = sigm(xr+hr);
      float zg = sigm(xz+hz);
      float ng = tanhf(xn + rg*hn);
      float hp = A_s[u*68 + row];
      o[uu] = (1.f - zg)*ng + zg*hp;
    }
    float4 ov = make_float4(o[0],o[1],o[2],o[3]);
    *(float4*)&hnext[(size_t)grow*64 + u0] = ov;
    if (WSEQ) *(float4*)&oseq[(size_t)grow*64 + u0] = ov;
    if (WFIN) {
      int bb = grow / N_;
      int nn = grow - bb*N_;
      *(float4*)&ofin[(((size_t)bb*T_ + t)*N_ + nn)*64 + u0] = ov;
    }
  }
}

// ---------------- stage C: fc2 MLP over out1 rows + nodevec = tanh(emb1*filt)
__global__ __launch_bounds__(256) void k_stageC(
    const float* __restrict__ out1, const float* __restrict__ emb1,
    const float* __restrict__ w1, const float* __restrict__ b1,
    const float* __restrict__ w2, const float* __restrict__ b2,
    const float* __restrict__ w3, const float* __restrict__ b3,
    float* __restrict__ ndv)
{
  int idx = blockIdx.x*256 + threadIdx.x;
  int m = idx % M_;
  int n = m % N_;
  float rv[64];
  const float4* r4 = (const float4*)(out1 + (size_t)idx*64);
  #pragma unroll
  for (int q=0;q<16;++q){ float4 v=r4[q]; rv[q*4]=v.x; rv[q*4+1]=v.y; rv[q*4+2]=v.z; rv[q*4+3]=v.w; }
  float h1[16];
  for (int u=0;u<16;++u){
    float a = b1[u];
    const float* wr = w1 + u*64;
    #pragma unroll
    for (int c=0;c<64;++c) a += rv[c]*wr[c];
    h1[u] = sigm(a);
  }
  float h2[2];
  #pragma unroll
  for (int v=0;v<2;++v){
    float a = b2[v];
    #pragma unroll
    for (int u=0;u<16;++u) a += h1[u]*w2[v*16+u];
    h2[v] = sigm(a);
  }
  #pragma unroll
  for (int d=0;d<10;++d){
    float f = b3[d] + h2[0]*w3[d*2] + h2[1]*w3[d*2+1];
    ndv[(size_t)idx*10 + d] = tanhf(emb1[n*10+d]*f);
  }
}

// ---------------- stage D: x_g = out1 + relu(V V^T) @ out1 per (t,b)
__global__ __launch_bounds__(256) void k_stageD(
    const float* __restrict__ ndv, const float* __restrict__ out1, float* __restrict__ xg)
{
  int tb = blockIdx.y;
  int tile = blockIdx.x;
  int tid = threadIdx.x;
  int r = tid & 63, cg = tid >> 6;
  __shared__ __align__(16) float V_s[307*12];
  for (int idx = tid; idx < 307*12; idx += 256) {
    int n = idx / 12, d = idx - n*12;
    V_s[idx] = (d < 10) ? ndv[((size_t)tb*N_ + n)*10 + d] : 0.f;
  }
  __syncthreads();
  int nrow = tile*64 + r;
  bool act = nrow < N_;
  float4 vr0 = make_float4(0,0,0,0), vr1 = vr0, vr2 = vr0;
  if (act) {
    vr0 = *(const float4*)&V_s[nrow*12];
    vr1 = *(const float4*)&V_s[nrow*12+4];
    vr2 = *(const float4*)&V_s[nrow*12+8];
  }
  float acc[16];
  #pragma unroll
  for (int q=0;q<16;++q) acc[q]=0.f;
  const float* ob = out1 + (size_t)tb*N_*64 + cg*16;
  for (int m=0; m<N_; ++m) {
    const float* vm = &V_s[m*12];
    float s = vr0.x*vm[0] + vr0.y*vm[1] + vr0.z*vm[2] + vr0.w*vm[3]
            + vr1.x*vm[4] + vr1.y*vm[5] + vr1.z*vm[6] + vr1.w*vm[7]
            + vr2.x*vm[8] + vr2.y*vm[9];
    s = fmaxf(s, 0.f);
    const float4* o4 = (const float4*)(ob + (size_t)m*64);
    float4 b0=o4[0], b1=o4[1], b2=o4[2], b3=o4[3];
    acc[0]+=s*b0.x; acc[1]+=s*b0.y; acc[2]+=s*b0.z; acc[3]+=s*b0.w;
    acc[4]+=s*b1.x; acc[5]+=s*b1.y; acc[6]+=s*b1.z; acc[7]+=s*b1.w;
    acc[8]+=s*b2.x; acc[9]+=s*b2.y; acc[10]+=s*b2.z; acc[11]+=s*b2.w;
    acc[12]+=s*b3.x; acc[13]+=s*b3.y; acc[14]+=s*b3.z; acc[15]+=s*b3.w;
  }
  if (act) {
    size_t base = ((size_t)tb*N_ + nrow)*64 + cg*16;
    const float4* i4 = (const float4*)(out1 + base);
    float4* w4 = (float4*)(xg + base);
    float4 r0=i4[0], r1=i4[1], r2=i4[2], r3=i4[3];
    w4[0] = make_float4(r0.x+acc[0],  r0.y+acc[1],  r0.z+acc[2],  r0.w+acc[3]);
    w4[1] = make_float4(r1.x+acc[4],  r1.y+acc[5],  r1.z+acc[6],  r1.w+acc[7]);
    w4[2] = make_float4(r2.x+acc[8],  r2.y+acc[9],  r2.z+acc[10], r2.w+acc[11]);
    w4[3] = make_float4(r3.x+acc[12], r3.y+acc[13], r3.z+acc[14], r3.w+acc[15]);
  }
}

// ---------------- stage E: diff1 = x_g @ Wn + bn ; g2_in = [out1,diff1] @ diff_w^T + diff_b (in-place over x_g)
__global__ __launch_bounds__(256) void k_stageE(
    const float* xg_in, const float* __restrict__ out1,
    const float* __restrict__ Wn, const float* __restrict__ bn,
    const float* __restrict__ dw, const float* __restrict__ db,
    float* xg_out)
{
  int n = blockIdx.y;
  int tile = blockIdx.x;     // 24 tiles of 32 tb-rows
  int tid = threadIdx.x;
  int r = tid & 31, ug = tid >> 5;
  __shared__ __align__(16) float x_s[32*68];
  __shared__ __align__(16) float o_s[32*68];
  __shared__ __align__(16) float W_s[64*68];    // transposed: [r_out][c]
  __shared__ __align__(16) float dw_s[64*132];
  __shared__ __align__(16) float d1_s[32*68];
  for (int idx=tid; idx<32*64; idx+=256){
    int row=idx>>6, c=idx&63;
    size_t g = ((size_t)(tile*32+row)*N_ + n)*64 + c;
    x_s[row*68+c] = xg_in[g];
    o_s[row*68+c] = out1[g];
  }
  for (int idx=tid; idx<4096; idx+=256){
    int c=idx>>6, u=idx&63;
    W_s[u*68+c] = Wn[(size_t)n*4096 + c*64 + u];
  }
  for (int idx=tid; idx<64*128; idx+=256){
    int u=idx>>7, c=idx&127;
    dw_s[u*132+c] = dw[u*128+c];
  }
  __syncthreads();
  float d1[8];
  #pragma unroll
  for (int uu=0;uu<8;++uu) d1[uu] = bn[n*64 + ug + 8*uu];
  for (int c=0;c<64;c+=4){
    float4 xc = *(const float4*)&x_s[r*68+c];
    #pragma unroll
    for (int uu=0;uu<8;++uu){
      float4 w = *(const float4*)&W_s[(ug+8*uu)*68 + c];
      d1[uu] += xc.x*w.x + xc.y*w.y + xc.z*w.z + xc.w*w.w;
    }
  }
  #pragma unroll
  for (int uu=0;uu<8;++uu) d1_s[r*68 + ug + 8*uu] = d1[uu];
  __syncthreads();
  float g2[8];
  #pragma unroll
  for (int uu=0;uu<8;++uu) g2[uu] = db[ug + 8*uu];
  for (int c=0;c<64;c+=4){
    float4 oc = *(const float4*)&o_s[r*68+c];
    float4 dc = *(const float4*)&d1_s[r*68+c];
    #pragma unroll
    for (int uu=0;uu<8;++uu){
      int u = ug + 8*uu;
      float4 w0 = *(const float4*)&dw_s[u*132 + c];
      float4 w1 = *(const float4*)&dw_s[u*132 + 64 + c];
      g2[uu] += oc.x*w0.x + oc.y*w0.y + oc.z*w0.z + oc.w*w0.w
              + dc.x*w1.x + dc.y*w1.y + dc.z*w1.z + dc.w*w1.w;
    }
  }
  size_t base = ((size_t)(tile*32+r)*N_ + n)*64;
  #pragma unroll
  for (int uu=0;uu<8;++uu) xg_out[base + ug + 8*uu] = g2[uu];
}

extern "C" void kernel_launch(void* const* d_in, const int* in_sizes, int n_in,
                              void* d_out, int out_size, void* d_ws, size_t ws_size,
                              hipStream_t stream)
{
  (void)in_sizes; (void)n_in; (void)out_size;
  const float* x    = (const float*)d_in[0];
  const float* emb1 = (const float*)d_in[1];
  const float* emb2 = (const float*)d_in[2];
  const float* xw1  = (const float*)d_in[3];
  const float* xb1  = (const float*)d_in[4];
  const float* xw2  = (const float*)d_in[5];
  const float* xb2  = (const float*)d_in[6];
  const float* xw3  = (const float*)d_in[7];
  const float* xb3  = (const float*)d_in[8];
  const float* fw1  = (const float*)d_in[9];
  const float* fb1  = (const float*)d_in[10];
  const float* fw2  = (const float*)d_in[11];
  const float* fb2  = (const float*)d_in[12];
  const float* fw3  = (const float*)d_in[13];
  const float* fb3  = (const float*)d_in[14];
  const float* c2w1 = (const float*)d_in[15];
  const float* c2b1 = (const float*)d_in[16];
  const float* c2w2 = (const float*)d_in[17];
  const float* c2b2 = (const float*)d_in[18];
  const float* c2w3 = (const float*)d_in[19];
  const float* c2b3 = (const float*)d_in[20];
  const float* g1wih= (const float*)d_in[21];
  const float* g1whh= (const float*)d_in[22];
  const float* g1bih= (const float*)d_in[23];
  const float* g1bhh= (const float*)d_in[24];
  const float* g2wih= (const float*)d_in[25];
  const float* g2whh= (const float*)d_in[26];
  const float* g2bih= (const float*)d_in[27];
  const float* g2bhh= (const float*)d_in[28];
  const float* wpool= (const float*)d_in[29];
  const float* bpool= (const float*)d_in[30];
  const float* dww  = (const float*)d_in[31];
  const float* dwb  = (const float*)d_in[32];
  float* out = (float*)d_out;

  float* ws = (float*)d_ws;
  float* g1_in = ws;                          // 2,357,760
  float* out1  = g1_in + (size_t)TM_*10;      // 15,089,664
  float* ndv   = out1 + (size_t)TM_*64;       // 2,357,760
  float* xg    = ndv + (size_t)TM_*10;        // 15,089,664
  float* Wn    = xg + (size_t)TM_*64;         // 1,257,472
  float* bn    = Wn + (size_t)N_*4096;        // 19,648
  float* ha    = bn + (size_t)N_*64;          // 1,257,472
  float* hb    = ha + (size_t)M_*64;          // 1,257,472
  size_t need = ((size_t)(hb + (size_t)M_*64 - ws)) * 4;
  if (ws_size < need) return;   // workspace too small: bench will flag; adjust next round

  k_stageA<<<TM_/256, 256, 0, stream>>>(x, xw1,xb1,xw2,xb2,xw3,xb3, fw1,fb1,fw2,fb2,fw3,fb3, g1_in);
  k_wn<<<N_, 256, 0, stream>>>(emb2, wpool, bpool, Wn, bn);

  hipMemsetAsync(ha, 0, (size_t)M_*64*sizeof(float), stream);
  {
    float* hc = ha; float* hn = hb;
    for (int t=0;t<T_;++t){
      k_gru<10,76,76,true,false><<<M_/64, 256, 0, stream>>>(
          g1_in + (size_t)t*M_*10, hc, hn, g1wih, g1whh, g1bih, g1bhh,
          out1 + (size_t)t*M_*64, nullptr, t);
      float* tmp = hc; hc = hn; hn = tmp;
    }
  }

  k_stageC<<<TM_/256, 256, 0, stream>>>(out1, emb1, c2w1,c2b1,c2w2,c2b2,c2w3,c2b3, ndv);
  k_stageD<<<dim3(5, T_*B_), 256, 0, stream>>>(ndv, out1, xg);
  k_stageE<<<dim3((T_*B_)/32, N_), 256, 0, stream>>>(xg, out1, Wn, bn, dww, dwb, xg);

  hipMemsetAsync(ha, 0, (size_t)M_*64*sizeof(float), stream);
  {
    float* hc = ha; float* hn = hb;
    for (int t=0;t<T_;++t){
      k_gru<64,128,132,false,true><<<M_/64, 256, 0, stream>>>(
          xg + (size_t)t*M_*64, hc, hn, g2wih, g2whh, g2bih, g2bhh,
          nullptr, out, t);
      float* tmp = hc; hc = hn; hn = tmp;
    }
  }
}

// Round 2
// 1738.472 us; speedup vs baseline: 1.2269x; 1.2269x over previous
//
#include <hip/hip_runtime.h>
#include <math.h>

#define B_ 64
#define T_ 12
#define N_ 307
#define I_ 3
#define R_ 64
#define D_ 10
#define M_ (B_*N_)      // 19648
#define TM_ (T_*M_)     // 235776

__device__ __forceinline__ float sigm(float x){ return 1.f/(1.f+__expf(-x)); }

// ---------------- stage A: x-embedding MLP + feature gram + fc1 MLP -> g1_in [T][M][10]
__global__ __launch_bounds__(256) void k_stageA(
    const float* __restrict__ x,
    const float* __restrict__ xw1, const float* __restrict__ xb1,
    const float* __restrict__ xw2, const float* __restrict__ xb2,
    const float* __restrict__ xw3, const float* __restrict__ xb3,
    const float* __restrict__ fw1, const float* __restrict__ fb1,
    const float* __restrict__ fw2, const float* __restrict__ fb2,
    const float* __restrict__ fw3, const float* __restrict__ fb3,
    float* __restrict__ g1)
{
  int idx = blockIdx.x*256 + threadIdx.x;      // t*M + m, exact grid
  int t = idx / M_;
  int m = idx - t*M_;
  int b = m / N_;
  int n = m - b*N_;
  const float* xp = x + (((size_t)b*T_ + t)*N_ + n)*I_;
  float xv[3] = {xp[0], xp[1], xp[2]};
  float e[3][10];
  #pragma unroll
  for (int i=0;i<3;++i){
    float h1[16];
    #pragma unroll
    for (int u=0;u<16;++u) h1[u] = sigm(xv[i]*xw1[u] + xb1[u]);
    float h2[2];
    #pragma unroll
    for (int v=0;v<2;++v){
      float a = xb2[v];
      #pragma unroll
      for (int u=0;u<16;++u) a += h1[u]*xw2[v*16+u];
      h2[v] = sigm(a);
    }
    #pragma unroll
    for (int d=0;d<10;++d) e[i][d] = xb3[d] + h2[0]*xw3[d*2] + h2[1]*xw3[d*2+1];
  }
  float in1[3];
  #pragma unroll
  for (int j=0;j<3;++j){
    float acc = 0.f;
    #pragma unroll
    for (int i=0;i<3;++i){
      float s = 0.f;
      #pragma unroll
      for (int d=0;d<10;++d) s += e[j][d]*e[i][d];
      s = fmaxf(s, 0.f);
      acc += s*xv[i];
    }
    in1[j] = xv[j] + acc;
  }
  float h1[16];
  #pragma unroll
  for (int u=0;u<16;++u)
    h1[u] = sigm(fb1[u] + in1[0]*fw1[u*3] + in1[1]*fw1[u*3+1] + in1[2]*fw1[u*3+2]);
  float h2[2];
  #pragma unroll
  for (int v=0;v<2;++v){
    float a = fb2[v];
    #pragma unroll
    for (int u=0;u<16;++u) a += h1[u]*fw2[v*16+u];
    h2[v] = sigm(a);
  }
  float* gp = g1 + (size_t)idx*10;
  #pragma unroll
  for (int d=0;d<10;++d) gp[d] = fb3[d] + h2[0]*fw3[d*2] + h2[1]*fw3[d*2+1];
}

// ---------------- per-node mixing matrices: Wn [N][64*64] (layout [c][r]), bn [N][64]
__global__ __launch_bounds__(256) void k_wn(
    const float* __restrict__ emb2, const float* __restrict__ wpool,
    const float* __restrict__ bpool, float* __restrict__ Wn, float* __restrict__ bn)
{
  int n = blockIdx.x; int tid = threadIdx.x;
  __shared__ float e_s[10];
  if (tid < 10) e_s[tid] = emb2[n*10 + tid];
  __syncthreads();
  #pragma unroll
  for (int e=0;e<16;++e){
    int i = e*256 + tid;            // 0..4095
    float a = 0.f;
    #pragma unroll
    for (int d=0;d<10;++d) a += e_s[d]*wpool[(size_t)d*4096 + i];
    Wn[(size_t)n*4096 + i] = a;
  }
  if (tid < 64){
    float a = 0.f;
    #pragma unroll
    for (int d=0;d<10;++d) a += e_s[d]*bpool[d*64 + tid];
    bn[n*64 + tid] = a;
  }
}

// ---------------- fused GRU step: [h | x] @ [whh | wih]^T with separate h/x accumulators
// block = 64 rows x 192 cols; thread (tr,tc): rows tr*4..+3, units tc*4..+3 (all 3 gates)
template<int DIN, int KP, int KS, bool WSEQ, bool WFIN>
__global__ __launch_bounds__(256) void k_gru(
    const float* __restrict__ xin, const float* __restrict__ hprev,
    float* __restrict__ hnext,
    const float* __restrict__ wih, const float* __restrict__ whh,
    const float* __restrict__ bih, const float* __restrict__ bhh,
    float* __restrict__ oseq, float* __restrict__ ofin, int t)
{
  __shared__ __align__(16) float W_s[192*KS];
  __shared__ __align__(16) float A_s[KP*68];
  const int tid = threadIdx.x;
  const int row0 = blockIdx.x * 64;

  for (int idx = tid; idx < 192*KP; idx += 256) {
    int col = idx / KP, k = idx - col*KP;
    float v = 0.f;
    if (k < 64) v = whh[col*64 + k];
    else if (k - 64 < DIN) v = wih[col*DIN + (k-64)];
    W_s[col*KS + k] = v;
  }
  for (int idx = tid; idx < 64*64; idx += 256) {
    int row = idx >> 6, k = idx & 63;
    A_s[k*68 + row] = hprev[(size_t)(row0+row)*64 + k];
  }
  constexpr int XK = KP - 64;
  for (int idx = tid; idx < 64*XK; idx += 256) {
    int row = idx / XK, kk = idx - row*XK;
    float v = (kk < DIN) ? xin[(size_t)(row0+row)*DIN + kk] : 0.f;
    A_s[(64+kk)*68 + row] = v;
  }
  __syncthreads();

  const int tr = tid & 15, tc = tid >> 4;
  const int u0 = tc * 4;
  const int tr4 = tr * 4;

  float acc_h[4][3][4];
  float acc_x[4][3][4];
  #pragma unroll
  for (int rr=0;rr<4;++rr)
    #pragma unroll
    for (int g=0;g<3;++g)
      #pragma unroll
      for (int uu=0;uu<4;++uu){ acc_h[rr][g][uu]=0.f; acc_x[rr][g][uu]=0.f; }

  for (int k=0; k<64; k+=4) {
    float4 a0 = *(const float4*)&A_s[(k+0)*68 + tr4];
    float4 a1 = *(const float4*)&A_s[(k+1)*68 + tr4];
    float4 a2 = *(const float4*)&A_s[(k+2)*68 + tr4];
    float4 a3 = *(const float4*)&A_s[(k+3)*68 + tr4];
    #pragma unroll
    for (int g=0;g<3;++g)
      #pragma unroll
      for (int uu=0;uu<4;++uu){
        float4 w = *(const float4*)&W_s[(g*64+u0+uu)*KS + k];
        acc_h[0][g][uu] += a0.x*w.x + a1.x*w.y + a2.x*w.z + a3.x*w.w;
        acc_h[1][g][uu] += a0.y*w.x + a1.y*w.y + a2.y*w.z + a3.y*w.w;
        acc_h[2][g][uu] += a0.z*w.x + a1.z*w.y + a2.z*w.z + a3.z*w.w;
        acc_h[3][g][uu] += a0.w*w.x + a1.w*w.y + a2.w*w.z + a3.w*w.w;
      }
  }
  for (int k=64; k<KP; k+=4) {
    float4 a0 = *(const float4*)&A_s[(k+0)*68 + tr4];
    float4 a1 = *(const float4*)&A_s[(k+1)*68 + tr4];
    float4 a2 = *(const float4*)&A_s[(k+2)*68 + tr4];
    float4 a3 = *(const float4*)&A_s[(k+3)*68 + tr4];
    #pragma unroll
    for (int g=0;g<3;++g)
      #pragma unroll
      for (int uu=0;uu<4;++uu){
        float4 w = *(const float4*)&W_s[(g*64+u0+uu)*KS + k];
        acc_x[0][g][uu] += a0.x*w.x + a1.x*w.y + a2.x*w.z + a3.x*w.w;
        acc_x[1][g][uu] += a0.y*w.x + a1.y*w.y + a2.y*w.z + a3.y*w.w;
        acc_x[2][g][uu] += a0.z*w.x + a1.z*w.y + a2.z*w.z + a3.z*w.w;
        acc_x[3][g][uu] += a0.w*w.x + a1.w*w.y + a2.w*w.z + a3.w*w.w;
      }
  }

  #pragma unroll
  for (int rr=0; rr<4; ++rr) {
    int row = tr4 + rr; int grow = row0 + row;
    float o[4];
    #pragma unroll
    for (int uu=0; uu<4; ++uu) {
      int u = u0+uu;
      float xr = acc_x[rr][0][uu] + bih[u];
      float hr = acc_h[rr][0][uu] + bhh[u];
      float xz = acc_x[rr][1][uu] + bih[64+u];
      float hz = acc_h[rr][1][uu] + bhh[64+u];
      float xn = acc_x[rr][2][uu] + bih[128+u];
      float hn = acc_h[rr][2][uu] + bhh[128+u];
      float rg = sigm(xr+hr);
      float zg = sigm(xz+hz);
      float ng = tanhf(xn + rg*hn);
      float hp = A_s[u*68 + row];
      o[uu] = (1.f - zg)*ng + zg*hp;
    }
    float4 ov = make_float4(o[0],o[1],o[2],o[3]);
    *(float4*)&hnext[(size_t)grow*64 + u0] = ov;
    if (WSEQ) *(float4*)&oseq[(size_t)grow*64 + u0] = ov;
    if (WFIN) {
      int bb = grow / N_;
      int nn = grow - bb*N_;
      *(float4*)&ofin[(((size_t)bb*T_ + t)*N_ + nn)*64 + u0] = ov;
    }
  }
}

// ---------------- stage C: fc2 MLP over out1 rows + nodevec = tanh(emb1*filt)
__global__ __launch_bounds__(256) void k_stageC(
    const float* __restrict__ out1, const float* __restrict__ emb1,
    const float* __restrict__ w1, const float* __restrict__ b1,
    const float* __restrict__ w2, const float* __restrict__ b2,
    const float* __restrict__ w3, const float* __restrict__ b3,
    float* __restrict__ ndv)
{
  int idx = blockIdx.x*256 + threadIdx.x;
  int m = idx % M_;
  int n = m % N_;
  float rv[64];
  const float4* r4 = (const float4*)(out1 + (size_t)idx*64);
  #pragma unroll
  for (int q=0;q<16;++q){ float4 v=r4[q]; rv[q*4]=v.x; rv[q*4+1]=v.y; rv[q*4+2]=v.z; rv[q*4+3]=v.w; }
  float h1[16];
  for (int u=0;u<16;++u){
    float a = b1[u];
    const float* wr = w1 + u*64;
    #pragma unroll
    for (int c=0;c<64;++c) a += rv[c]*wr[c];
    h1[u] = sigm(a);
  }
  float h2[2];
  #pragma unroll
  for (int v=0;v<2;++v){
    float a = b2[v];
    #pragma unroll
    for (int u=0;u<16;++u) a += h1[u]*w2[v*16+u];
    h2[v] = sigm(a);
  }
  #pragma unroll
  for (int d=0;d<10;++d){
    float f = b3[d] + h2[0]*w3[d*2] + h2[1]*w3[d*2+1];
    ndv[(size_t)idx*10 + d] = tanhf(emb1[n*10+d]*f);
  }
}

// ---------------- stage D: x_g = out1 + relu(V V^T) @ out1 per (t,b)
// LDS-tiled GEMM: 64-row tile x 64 cols, chunks of 64 m staged in LDS,
// s(n,m) computed once cooperatively, 4x4 register tile per thread.
__global__ __launch_bounds__(256) void k_stageD(
    const float* __restrict__ ndv, const float* __restrict__ out1, float* __restrict__ xg)
{
  int tb = blockIdx.y;
  int tile = blockIdx.x;               // 0..4
  int tid = threadIdx.x;
  __shared__ __align__(16) float V_s[320*12];
  __shared__ __align__(16) float o_s[64*68];
  __shared__ __align__(16) float s_s[64*68];   // s_s[m][row-within-tile]

  for (int i = tid; i < 320*12; i += 256) {
    int n = i / 12, d = i - n*12;
    V_s[i] = (n < N_ && d < 10) ? ndv[((size_t)tb*N_ + n)*10 + d] : 0.f;
  }
  __syncthreads();

  const int sr  = tid & 63;            // s-phase: row within tile
  const int smg = tid >> 6;            // s-phase: m-group (16 m's)
  float vr[10];
  {
    const float* vp = &V_s[(tile*64 + sr)*12];
    #pragma unroll
    for (int d = 0; d < 10; ++d) vr[d] = vp[d];
  }
  const int rq = tid & 15, cq = tid >> 4;
  const int r4 = rq*4, c4 = cq*4;
  float acc[4][4];
  #pragma unroll
  for (int a=0;a<4;++a)
    #pragma unroll
    for (int b=0;b<4;++b) acc[a][b]=0.f;

  for (int mc = 0; mc < 320; mc += 64) {
    __syncthreads();
    // stage out1 chunk rows mc..mc+63 (coalesced float4, zero-pad tail)
    for (int i = tid; i < 1024; i += 256) {
      int row = i >> 4, f4 = i & 15;
      int gm = mc + row;
      float4 v = make_float4(0.f,0.f,0.f,0.f);
      if (gm < N_) v = *(const float4*)&out1[((size_t)tb*N_ + gm)*64 + f4*4];
      *(float4*)&o_s[row*68 + f4*4] = v;
    }
    // s chunk: each thread 16 m's for its own row
    #pragma unroll
    for (int j = 0; j < 16; ++j) {
      int m = smg*16 + j;
      const float* vm = &V_s[(mc + m)*12];
      float s = vr[0]*vm[0] + vr[1]*vm[1] + vr[2]*vm[2] + vr[3]*vm[3] + vr[4]*vm[4]
              + vr[5]*vm[5] + vr[6]*vm[6] + vr[7]*vm[7] + vr[8]*vm[8] + vr[9]*vm[9];
      s_s[m*68 + sr] = fmaxf(s, 0.f);
    }
    __syncthreads();
    // accumulate 4x4 register tile
    #pragma unroll 8
    for (int m = 0; m < 64; ++m) {
      float4 sv = *(const float4*)&s_s[m*68 + r4];
      float4 ov = *(const float4*)&o_s[m*68 + c4];
      acc[0][0] += sv.x*ov.x; acc[0][1] += sv.x*ov.y; acc[0][2] += sv.x*ov.z; acc[0][3] += sv.x*ov.w;
      acc[1][0] += sv.y*ov.x; acc[1][1] += sv.y*ov.y; acc[1][2] += sv.y*ov.z; acc[1][3] += sv.y*ov.w;
      acc[2][0] += sv.z*ov.x; acc[2][1] += sv.z*ov.y; acc[2][2] += sv.z*ov.z; acc[2][3] += sv.z*ov.w;
      acc[3][0] += sv.w*ov.x; acc[3][1] += sv.w*ov.y; acc[3][2] += sv.w*ov.z; acc[3][3] += sv.w*ov.w;
    }
  }

  #pragma unroll
  for (int rr = 0; rr < 4; ++rr) {
    int nrow = tile*64 + r4 + rr;
    if (nrow < N_) {
      size_t base = ((size_t)tb*N_ + nrow)*64 + c4;
      float4 o = *(const float4*)&out1[base];
      *(float4*)&xg[base] = make_float4(o.x+acc[rr][0], o.y+acc[rr][1],
                                        o.z+acc[rr][2], o.w+acc[rr][3]);
    }
  }
}

// ---------------- stage E: diff1 = x_g @ Wn + bn ; g2_in = [out1,diff1] @ diff_w^T + diff_b (in-place over x_g)
__global__ __launch_bounds__(256) void k_stageE(
    const float* xg_in, const float* __restrict__ out1,
    const float* __restrict__ Wn, const float* __restrict__ bn,
    const float* __restrict__ dw, const float* __restrict__ db,
    float* xg_out)
{
  int n = blockIdx.y;
  int tile = blockIdx.x;     // 24 tiles of 32 tb-rows
  int tid = threadIdx.x;
  int r = tid & 31, ug = tid >> 5;
  __shared__ __align__(16) float x_s[32*68];
  __shared__ __align__(16) float o_s[32*68];
  __shared__ __align__(16) float W_s[64*68];    // transposed: [r_out][c]
  __shared__ __align__(16) float dw_s[64*132];
  __shared__ __align__(16) float d1_s[32*68];
  for (int idx=tid; idx<32*64; idx+=256){
    int row=idx>>6, c=idx&63;
    size_t g = ((size_t)(tile*32+row)*N_ + n)*64 + c;
    x_s[row*68+c] = xg_in[g];
    o_s[row*68+c] = out1[g];
  }
  for (int idx=tid; idx<4096; idx+=256){
    int c=idx>>6, u=idx&63;
    W_s[u*68+c] = Wn[(size_t)n*4096 + c*64 + u];
  }
  for (int idx=tid; idx<64*128; idx+=256){
    int u=idx>>7, c=idx&127;
    dw_s[u*132+c] = dw[u*128+c];
  }
  __syncthreads();
  float d1[8];
  #pragma unroll
  for (int uu=0;uu<8;++uu) d1[uu] = bn[n*64 + ug + 8*uu];
  for (int c=0;c<64;c+=4){
    float4 xc = *(const float4*)&x_s[r*68+c];
    #pragma unroll
    for (int uu=0;uu<8;++uu){
      float4 w = *(const float4*)&W_s[(ug+8*uu)*68 + c];
      d1[uu] += xc.x*w.x + xc.y*w.y + xc.z*w.z + xc.w*w.w;
    }
  }
  #pragma unroll
  for (int uu=0;uu<8;++uu) d1_s[r*68 + ug + 8*uu] = d1[uu];
  __syncthreads();
  float g2[8];
  #pragma unroll
  for (int uu=0;uu<8;++uu) g2[uu] = db[ug + 8*uu];
  for (int c=0;c<64;c+=4){
    float4 oc = *(const float4*)&o_s[r*68+c];
    float4 dc = *(const float4*)&d1_s[r*68+c];
    #pragma unroll
    for (int uu=0;uu<8;++uu){
      int u = ug + 8*uu;
      float4 w0 = *(const float4*)&dw_s[u*132 + c];
      float4 w1 = *(const float4*)&dw_s[u*132 + 64 + c];
      g2[uu] += oc.x*w0.x + oc.y*w0.y + oc.z*w0.z + oc.w*w0.w
              + dc.x*w1.x + dc.y*w1.y + dc.z*w1.z + dc.w*w1.w;
    }
  }
  size_t base = ((size_t)(tile*32+r)*N_ + n)*64;
  #pragma unroll
  for (int uu=0;uu<8;++uu) xg_out[base + ug + 8*uu] = g2[uu];
}

extern "C" void kernel_launch(void* const* d_in, const int* in_sizes, int n_in,
                              void* d_out, int out_size, void* d_ws, size_t ws_size,
                              hipStream_t stream)
{
  (void)in_sizes; (void)n_in; (void)out_size;
  const float* x    = (const float*)d_in[0];
  const float* emb1 = (const float*)d_in[1];
  const float* emb2 = (const float*)d_in[2];
  const float* xw1  = (const float*)d_in[3];
  const float* xb1  = (const float*)d_in[4];
  const float* xw2  = (const float*)d_in[5];
  const float* xb2  = (const float*)d_in[6];
  const float* xw3  = (const float*)d_in[7];
  const float* xb3  = (const float*)d_in[8];
  const float* fw1  = (const float*)d_in[9];
  const float* fb1  = (const float*)d_in[10];
  const float* fw2  = (const float*)d_in[11];
  const float* fb2  = (const float*)d_in[12];
  const float* fw3  = (const float*)d_in[13];
  const float* fb3  = (const float*)d_in[14];
  const float* c2w1 = (const float*)d_in[15];
  const float* c2b1 = (const float*)d_in[16];
  const float* c2w2 = (const float*)d_in[17];
  const float* c2b2 = (const float*)d_in[18];
  const float* c2w3 = (const float*)d_in[19];
  const float* c2b3 = (const float*)d_in[20];
  const float* g1wih= (const float*)d_in[21];
  const float* g1whh= (const float*)d_in[22];
  const float* g1bih= (const float*)d_in[23];
  const float* g1bhh= (const float*)d_in[24];
  const float* g2wih= (const float*)d_in[25];
  const float* g2whh= (const float*)d_in[26];
  const float* g2bih= (const float*)d_in[27];
  const float* g2bhh= (const float*)d_in[28];
  const float* wpool= (const float*)d_in[29];
  const float* bpool= (const float*)d_in[30];
  const float* dww  = (const float*)d_in[31];
  const float* dwb  = (const float*)d_in[32];
  float* out = (float*)d_out;

  float* ws = (float*)d_ws;
  float* g1_in = ws;                          // 2,357,760
  float* out1  = g1_in + (size_t)TM_*10;      // 15,089,664
  float* ndv   = out1 + (size_t)TM_*64;       // 2,357,760
  float* xg    = ndv + (size_t)TM_*10;        // 15,089,664
  float* Wn    = xg + (size_t)TM_*64;         // 1,257,472
  float* bn    = Wn + (size_t)N_*4096;        // 19,648
  float* ha    = bn + (size_t)N_*64;          // 1,257,472
  float* hb    = ha + (size_t)M_*64;          // 1,257,472
  size_t need = ((size_t)(hb + (size_t)M_*64 - ws)) * 4;
  if (ws_size < need) return;

  k_stageA<<<TM_/256, 256, 0, stream>>>(x, xw1,xb1,xw2,xb2,xw3,xb3, fw1,fb1,fw2,fb2,fw3,fb3, g1_in);
  k_wn<<<N_, 256, 0, stream>>>(emb2, wpool, bpool, Wn, bn);

  hipMemsetAsync(ha, 0, (size_t)M_*64*sizeof(float), stream);
  {
    float* hc = ha; float* hn = hb;
    for (int t=0;t<T_;++t){
      k_gru<10,76,76,true,false><<<M_/64, 256, 0, stream>>>(
          g1_in + (size_t)t*M_*10, hc, hn, g1wih, g1whh, g1bih, g1bhh,
          out1 + (size_t)t*M_*64, nullptr, t);
      float* tmp = hc; hc = hn; hn = tmp;
    }
  }

  k_stageC<<<TM_/256, 256, 0, stream>>>(out1, emb1, c2w1,c2b1,c2w2,c2b2,c2w3,c2b3, ndv);
  k_stageD<<<dim3(5, T_*B_), 256, 0, stream>>>(ndv, out1, xg);
  k_stageE<<<dim3((T_*B_)/32, N_), 256, 0, stream>>>(xg, out1, Wn, bn, dww, dwb, xg);

  hipMemsetAsync(ha, 0, (size_t)M_*64*sizeof(float), stream);
  {
    float* hc = ha; float* hn = hb;
    for (int t=0;t<T_;++t){
      k_gru<64,128,132,false,true><<<M_/64, 256, 0, stream>>>(
          xg + (size_t)t*M_*64, hc, hn, g2wih, g2whh, g2bih, g2bhh,
          nullptr, out, t);
      float* tmp = hc; hc = hn; hn = tmp;
    }
  }
}